// Round 5
// baseline (215.255 us; speedup 1.0000x reference)
//
#include <hip/hip_runtime.h>
#include <hip/hip_cooperative_groups.h>
#include <hip/hip_fp16.h>
#include <math.h>

#define EPSV 1e-6f
#define TPB 256
#define SLICES 32          // gaussian slices (grid.y)
#define PPT 4              // pixels per thread (2 x float2 packed groups)
#define GRP 2              // PPT/2 vec2 groups
#define GCAP 256           // max gaussians per slice supported in LDS

typedef float v2f __attribute__((ext_vector_type(2)));

// Per-gaussian packed params: 8 dwords (2 x float4) in LDS:
//   q0 = (na, nb, nc, nd)   q1 = (ne, nf, half2(cr,cg), half2(cb,0))
// w = exp2(na*px^2 + nb*py^2 + nc*px*py + nd*px + ne*py + nf)
//   = exp(-0.5*((u/sx)^2 + (v/sy)^2)); colors pre-multiplied by alpha.
// Inner loop uses float2 ext-vectors -> v_pk_fma_f32 (2 FP32/lane/instr);
// only v_exp_f32 stays scalar. Single cooperative kernel: splat partials,
// grid sync, then in-place 32-slice reduction (saves the 2nd launch).

__device__ __forceinline__ float pack_half2(float a, float b) {
    __half2 h = __floats2half2_rn(a, b);
    union { __half2 h; float f; } u; u.h = h;
    return u.f;
}

__global__ __launch_bounds__(TPB) void splat_coop(
        const float* __restrict__ pos,
        const float* __restrict__ col,
        const float* __restrict__ ls,
        const float* __restrict__ rot,
        const float* __restrict__ alph,
        const int* __restrict__ nact_p,
        const int* __restrict__ hptr,
        const int* __restrict__ wptr,
        float* __restrict__ partial,   // [SLICES][3][P]
        float* __restrict__ out,
        int N, int P, int g_per_slice, int total4) {
    __shared__ float4 sh[GCAP * 2];

    const int slice = blockIdx.y;
    const int t = threadIdx.x;

    // ---- per-block preprocessing of this slice's gaussians (1/thread) ----
    int nact = *nact_p;
    for (int j = t; j < g_per_slice; j += TPB) {
        int g = slice * g_per_slice + j;
        float4 o0 = make_float4(0.f, 0.f, 0.f, 0.f);
        float4 o1 = o0;   // colors 0 -> contribution 0 even though exp2(0)=1
        if (g < N && g < nact) {
            float sx = expf(ls[2 * g])     + EPSV;
            float sy = expf(ls[2 * g + 1]) + EPSV;
            float r  = rot[g];
            float c = cosf(r), s = sinf(r);
            const float K = 0.84932180028801904f;  // sqrt(0.5*log2(e))
            float iA =  K * c / sx;
            float iB =  K * s / sx;
            float iC = -K * s / sy;
            float iD =  K * c / sy;
            float px = pos[2 * g], py = pos[2 * g + 1];
            float E = -(iA * px + iB * py);
            float F = -(iC * px + iD * py);
            float a  = iA * iA + iC * iC;
            float b  = iB * iB + iD * iD;
            float cc = 2.0f * (iA * iB + iC * iD);
            float d  = 2.0f * (iA * E + iC * F);
            float e  = 2.0f * (iB * E + iD * F);
            float f  = E * E + F * F;
            float al = alph[g];
            float cr = al * col[3 * g];
            float cg = al * col[3 * g + 1];
            float cb = al * col[3 * g + 2];
            o0 = make_float4(-a, -b, -cc, -d);
            o1 = make_float4(-e, -f, pack_half2(cr, cg), pack_half2(cb, 0.f));
        }
        sh[2 * j]     = o0;
        sh[2 * j + 1] = o1;
    }
    __syncthreads();

    // ---- per-thread pixel constants: GRP groups of 2 pixels (float2) ----
    const int W = *wptr;
    const int H = *hptr;
    const int base = blockIdx.x * (TPB * PPT);
    v2f px2[GRP], py2[GRP], pxx2[GRP], pyy2[GRP], pxy2[GRP];
#pragma unroll
    for (int k = 0; k < GRP; ++k) {
#pragma unroll
        for (int e = 0; e < 2; ++e) {
            int p = base + t + (2 * k + e) * TPB;
            int x = (p < P) ? (p % W) : 0;
            int y = (p < P) ? (p / W) : 0;
            float fx = -1.0f + (float)x * (2.0f / (float)(W - 1));
            float fy = -1.0f + (float)y * (2.0f / (float)(H - 1));
            px2[k][e] = fx;  py2[k][e] = fy;
            pxx2[k][e] = fx * fx;  pyy2[k][e] = fy * fy;  pxy2[k][e] = fx * fy;
        }
    }

    v2f accr2[GRP], accg2[GRP], accb2[GRP];
#pragma unroll
    for (int k = 0; k < GRP; ++k) {
        accr2[k] = (v2f)(0.f); accg2[k] = (v2f)(0.f); accb2[k] = (v2f)(0.f);
    }

    // ---- main loop: broadcast LDS reads, packed-fp32 math ----
#pragma unroll 2
    for (int g = 0; g < g_per_slice; ++g) {
        float4 a0 = sh[2 * g];
        float4 a1 = sh[2 * g + 1];

        union { float f; __half2 h; } u01, u2x;
        u01.f = a1.z; u2x.f = a1.w;
        float cr = __low2float(u01.h);
        float cg = __high2float(u01.h);
        float cb = __low2float(u2x.h);

        v2f CA = {a0.x, a0.x}, CB = {a0.y, a0.y}, CC = {a0.z, a0.z};
        v2f CD = {a0.w, a0.w}, CE = {a1.x, a1.x}, CF = {a1.y, a1.y};
        v2f CR = {cr, cr}, CG = {cg, cg}, CBL = {cb, cb};

#pragma unroll
        for (int k = 0; k < GRP; ++k) {
            v2f tt = pxx2[k] * CA + CF;
            tt = pyy2[k] * CB + tt;
            tt = pxy2[k] * CC + tt;
            tt = px2[k]  * CD + tt;
            tt = py2[k]  * CE + tt;
            v2f w;
            w[0] = __builtin_amdgcn_exp2f(tt[0]);
            w[1] = __builtin_amdgcn_exp2f(tt[1]);
            accr2[k] = w * CR  + accr2[k];
            accg2[k] = w * CG  + accg2[k];
            accb2[k] = w * CBL + accb2[k];
        }
    }

    // ---- private partial-sum stores (no atomics, no init needed) ----
    float* dst = partial + (size_t)slice * 3 * P;
#pragma unroll
    for (int k = 0; k < GRP; ++k) {
#pragma unroll
        for (int e = 0; e < 2; ++e) {
            int p = base + t + (2 * k + e) * TPB;
            if (p < P) {
                dst[p]         = accr2[k][e];
                dst[P + p]     = accg2[k][e];
                dst[2 * P + p] = accb2[k][e];
            }
        }
    }

    // ---- grid-wide sync, then in-place reduction by first total4 threads ----
    __threadfence();   // make partials visible device-wide (cross-XCD)
    cooperative_groups::this_grid().sync();

    int lin_block = blockIdx.y * gridDim.x + blockIdx.x;
    int i = lin_block * TPB + t;
    if (i < total4) {
        const float4* p4 = (const float4*)partial;
        float4 s = make_float4(-1.f, -1.f, -1.f, -1.f);  // render - 1 folded
#pragma unroll
        for (int sl = 0; sl < SLICES; ++sl) {
            float4 v = p4[(size_t)sl * total4 + i];
            s.x += v.x; s.y += v.y; s.z += v.z; s.w += v.w;
        }
        ((float4*)out)[i] = s;
    }
}

extern "C" void kernel_launch(void* const* d_in, const int* in_sizes, int n_in,
                              void* d_out, int out_size, void* d_ws, size_t ws_size,
                              hipStream_t stream) {
    const float* pos  = (const float*)d_in[0];
    const float* col  = (const float*)d_in[1];
    const float* ls   = (const float*)d_in[2];
    const float* rot  = (const float*)d_in[3];
    const float* alph = (const float*)d_in[4];
    const int*   hptr = (const int*)d_in[5];
    const int*   wptr = (const int*)d_in[6];
    const int*   nact = (const int*)d_in[7];

    int N = in_sizes[3];           // rotation has one entry per gaussian
    int P = out_size / 3;          // pixels

    int g_per_slice = (N + SLICES - 1) / SLICES;   // 128 for N=4096
    if (g_per_slice > GCAP) g_per_slice = GCAP;    // capacity guard

    float* partial = (float*)d_ws;  // SLICES * out_size floats (~6.3 MB)
    float* out = (float*)d_out;
    int total4 = out_size / 4;

    int px_blocks = (P + TPB * PPT - 1) / (TPB * PPT);   // 16 for P=16384
    dim3 grid(px_blocks, SLICES);                        // 512 blocks, 2/CU
    dim3 block(TPB);

    void* args[] = {
        (void*)&pos, (void*)&col, (void*)&ls, (void*)&rot, (void*)&alph,
        (void*)&nact, (void*)&hptr, (void*)&wptr,
        (void*)&partial, (void*)&out,
        (void*)&N, (void*)&P, (void*)&g_per_slice, (void*)&total4,
    };
    hipLaunchCooperativeKernel((const void*)splat_coop, grid, block,
                               args, 0, stream);
}

// Round 6
// 90.019 us; speedup vs baseline: 2.3912x; 2.3912x over previous
//
#include <hip/hip_runtime.h>
#include <hip/hip_fp16.h>
#include <math.h>

#define EPSV 1e-6f
#define TPB 256
#define SLICES 32          // gaussian slices (grid.y)
#define PPT 4              // pixels per thread (2 x float2 packed groups)
#define GRP 2              // PPT/2 vec2 groups
#define GCAP 256           // max gaussians per slice supported in LDS

typedef float v2f __attribute__((ext_vector_type(2)));

// Per-gaussian packed params: 8 dwords (2 x float4) in LDS:
//   q0 = (na, nb, nc, nd)   q1 = (ne, nf, half2(cr,cg), half2(cb,0))
// w = exp2(na*px^2 + nb*py^2 + nc*px*py + nd*px + ne*py + nf)
//   = exp(-0.5*((u/sx)^2 + (v/sy)^2)); colors pre-multiplied by alpha.
// Inner loop uses float2 ext-vectors -> v_pk_fma_f32; only v_exp_f32 scalar.
// Epilogue: 3 float atomicAdds/pixel into d_out, which is pre-set to -1.0f
// via hipMemsetD32Async (folds the "render - 1" and removes the reduce pass).

__device__ __forceinline__ float pack_half2(float a, float b) {
    __half2 h = __floats2half2_rn(a, b);
    union { __half2 h; float f; } u; u.h = h;
    return u.f;
}

__global__ __launch_bounds__(TPB) void splat_fused(
        const float* __restrict__ pos,
        const float* __restrict__ col,
        const float* __restrict__ ls,
        const float* __restrict__ rot,
        const float* __restrict__ alph,
        const int* __restrict__ nact_p,
        const int* __restrict__ hptr,
        const int* __restrict__ wptr,
        float* __restrict__ out,       // pre-initialized to -1.0f
        int N, int P, int g_per_slice) {
    __shared__ float4 sh[GCAP * 2];

    const int slice = blockIdx.y;
    const int t = threadIdx.x;

    // ---- per-block preprocessing of this slice's gaussians (1/thread) ----
    int nact = *nact_p;
    for (int j = t; j < g_per_slice; j += TPB) {
        int g = slice * g_per_slice + j;
        float4 o0 = make_float4(0.f, 0.f, 0.f, 0.f);
        float4 o1 = o0;   // colors 0 -> contribution 0 even though exp2(0)=1
        if (g < N && g < nact) {
            float sx = expf(ls[2 * g])     + EPSV;
            float sy = expf(ls[2 * g + 1]) + EPSV;
            float r  = rot[g];
            float c = cosf(r), s = sinf(r);
            const float K = 0.84932180028801904f;  // sqrt(0.5*log2(e))
            float iA =  K * c / sx;
            float iB =  K * s / sx;
            float iC = -K * s / sy;
            float iD =  K * c / sy;
            float px = pos[2 * g], py = pos[2 * g + 1];
            float E = -(iA * px + iB * py);
            float F = -(iC * px + iD * py);
            float a  = iA * iA + iC * iC;
            float b  = iB * iB + iD * iD;
            float cc = 2.0f * (iA * iB + iC * iD);
            float d  = 2.0f * (iA * E + iC * F);
            float e  = 2.0f * (iB * E + iD * F);
            float f  = E * E + F * F;
            float al = alph[g];
            float cr = al * col[3 * g];
            float cg = al * col[3 * g + 1];
            float cb = al * col[3 * g + 2];
            o0 = make_float4(-a, -b, -cc, -d);
            o1 = make_float4(-e, -f, pack_half2(cr, cg), pack_half2(cb, 0.f));
        }
        sh[2 * j]     = o0;
        sh[2 * j + 1] = o1;
    }
    __syncthreads();

    // ---- per-thread pixel constants: GRP groups of 2 pixels (float2) ----
    const int W = *wptr;
    const int H = *hptr;
    const int base = blockIdx.x * (TPB * PPT);
    v2f px2[GRP], py2[GRP], pxx2[GRP], pyy2[GRP], pxy2[GRP];
#pragma unroll
    for (int k = 0; k < GRP; ++k) {
#pragma unroll
        for (int e = 0; e < 2; ++e) {
            int p = base + t + (2 * k + e) * TPB;
            int x = (p < P) ? (p % W) : 0;
            int y = (p < P) ? (p / W) : 0;
            float fx = -1.0f + (float)x * (2.0f / (float)(W - 1));
            float fy = -1.0f + (float)y * (2.0f / (float)(H - 1));
            px2[k][e] = fx;  py2[k][e] = fy;
            pxx2[k][e] = fx * fx;  pyy2[k][e] = fy * fy;  pxy2[k][e] = fx * fy;
        }
    }

    v2f accr2[GRP], accg2[GRP], accb2[GRP];
#pragma unroll
    for (int k = 0; k < GRP; ++k) {
        accr2[k] = (v2f)(0.f); accg2[k] = (v2f)(0.f); accb2[k] = (v2f)(0.f);
    }

    // ---- main loop: broadcast LDS reads, packed-fp32 math ----
#pragma unroll 2
    for (int g = 0; g < g_per_slice; ++g) {
        float4 a0 = sh[2 * g];
        float4 a1 = sh[2 * g + 1];

        union { float f; __half2 h; } u01, u2x;
        u01.f = a1.z; u2x.f = a1.w;
        float cr = __low2float(u01.h);
        float cg = __high2float(u01.h);
        float cb = __low2float(u2x.h);

        v2f CA = {a0.x, a0.x}, CB = {a0.y, a0.y}, CC = {a0.z, a0.z};
        v2f CD = {a0.w, a0.w}, CE = {a1.x, a1.x}, CF = {a1.y, a1.y};
        v2f CR = {cr, cr}, CG = {cg, cg}, CBL = {cb, cb};

#pragma unroll
        for (int k = 0; k < GRP; ++k) {
            v2f tt = pxx2[k] * CA + CF;
            tt = pyy2[k] * CB + tt;
            tt = pxy2[k] * CC + tt;
            tt = px2[k]  * CD + tt;
            tt = py2[k]  * CE + tt;
            v2f w;
            w[0] = __builtin_amdgcn_exp2f(tt[0]);
            w[1] = __builtin_amdgcn_exp2f(tt[1]);
            accr2[k] = w * CR  + accr2[k];
            accg2[k] = w * CG  + accg2[k];
            accb2[k] = w * CBL + accb2[k];
        }
    }

    // ---- atomic accumulate into pre-initialized output ----
#pragma unroll
    for (int k = 0; k < GRP; ++k) {
#pragma unroll
        for (int e = 0; e < 2; ++e) {
            int p = base + t + (2 * k + e) * TPB;
            if (p < P) {
                atomicAdd(&out[p],         accr2[k][e]);
                atomicAdd(&out[P + p],     accg2[k][e]);
                atomicAdd(&out[2 * P + p], accb2[k][e]);
            }
        }
    }
}

extern "C" void kernel_launch(void* const* d_in, const int* in_sizes, int n_in,
                              void* d_out, int out_size, void* d_ws, size_t ws_size,
                              hipStream_t stream) {
    const float* pos  = (const float*)d_in[0];
    const float* col  = (const float*)d_in[1];
    const float* ls   = (const float*)d_in[2];
    const float* rot  = (const float*)d_in[3];
    const float* alph = (const float*)d_in[4];
    const int*   hptr = (const int*)d_in[5];
    const int*   wptr = (const int*)d_in[6];
    const int*   nact = (const int*)d_in[7];

    int N = in_sizes[3];           // rotation has one entry per gaussian
    int P = out_size / 3;          // pixels

    int g_per_slice = (N + SLICES - 1) / SLICES;   // 128 for N=4096
    if (g_per_slice > GCAP) g_per_slice = GCAP;    // capacity guard

    // out[] = -1.0f everywhere (0xBF800000), folding the "render - 1".
    hipMemsetD32Async((hipDeviceptr_t)d_out, 0xBF800000, (size_t)out_size,
                      stream);

    int px_blocks = (P + TPB * PPT - 1) / (TPB * PPT);   // 16 for P=16384
    dim3 grid(px_blocks, SLICES);                        // 512 blocks
    splat_fused<<<grid, TPB, 0, stream>>>(
        pos, col, ls, rot, alph, nact, hptr, wptr, (float*)d_out,
        N, P, g_per_slice);
}